// Round 2
// baseline (168.789 us; speedup 1.0000x reference)
//
#include <hip/hip_runtime.h>
#include <math.h>

#define C 8192
#define D 1024
#define BATCH 1024
#define PM 0.95f
#define PMC 0.05f
// values pre-scaled by 8 before fp8 quant; dot comes out 64x too big.
// epilogue uses 10/64 = 0.15625 (exact in fp32).
#define INVT_SCALED 0.15625f

typedef unsigned char u8;
typedef __attribute__((ext_vector_type(16))) float f32x16;

#define GLOBAL_AS(p) ((const __attribute__((address_space(1))) void*)(p))
#define LDS_AS(p) ((__attribute__((address_space(3))) void*)(p))

// ---------------------------------------------------------------------------
// EMA + fp8 quantize, one wave per class (4 classes/block, 2048 blocks).
// Verified rounds 7-13. fp8 layout (512-B k-units for 32x32x16 fp8 MFMA):
//   element (row c, k) -> P8[(c>>5)*32768 + (k>>4)*512 + ((k>>3)&1)*256 + (c&31)*8 + (k&7)]
__global__ __launch_bounds__(256) void ema_split_kernel(const float* __restrict__ feat,
                                                        const int* __restrict__ labels,
                                                        const float* __restrict__ protos,
                                                        u8* __restrict__ P8,
                                                        float* __restrict__ rowsum,
                                                        float* __restrict__ out) {
    __shared__ int sl[BATCH];
    const int t = threadIdx.x, w = t >> 6, lane = t & 63;
    const int c = blockIdx.x * 4 + w;

    if (blockIdx.x < 32) rowsum[blockIdx.x * 256 + t] = 0.0f;
    if (blockIdx.x == 0 && t == 0) out[0] = 0.0f;

    for (int i = t; i < BATCH; i += 256) sl[i] = labels[i];
    __syncthreads();

    float4 v[4];
    #pragma unroll
    for (int s = 0; s < 4; ++s)
        v[s] = *(const float4*)(protos + (size_t)c * D + s * 256 + lane * 4);

    for (int base = 0; base < BATCH; base += 64) {
        unsigned long long mask = __ballot(sl[base + lane] == c);
        while (mask) {
            const int b = __ffsll((long long)mask) - 1;
            mask &= mask - 1;
            const int idx = base + b;
            float ss = 0.0f;
            #pragma unroll
            for (int s = 0; s < 4; ++s) {
                const float4 f = *(const float4*)(feat + (size_t)idx * D + s * 256 + lane * 4);
                v[s].x = v[s].x * PM + f.x * PMC;
                v[s].y = v[s].y * PM + f.y * PMC;
                v[s].z = v[s].z * PM + f.z * PMC;
                v[s].w = v[s].w * PM + f.w * PMC;
                ss += v[s].x * v[s].x + v[s].y * v[s].y + v[s].z * v[s].z + v[s].w * v[s].w;
            }
            #pragma unroll
            for (int off = 32; off > 0; off >>= 1) ss += __shfl_xor(ss, off);
            const float inv = 1.0f / fmaxf(sqrtf(ss), 1e-12f);
            #pragma unroll
            for (int s = 0; s < 4; ++s) {
                v[s].x *= inv; v[s].y *= inv; v[s].z *= inv; v[s].w *= inv;
            }
        }
    }

    u8* ob = P8 + (size_t)(c >> 5) * 32768 + (c & 31) * 8;
    #pragma unroll
    for (int s = 0; s < 4; ++s) {
        const int k0 = s * 256 + lane * 4;
        const size_t off = (size_t)(k0 >> 4) * 512 + ((k0 >> 3) & 1) * 256 + (k0 & 7);
        int p = __builtin_amdgcn_cvt_pk_fp8_f32(v[s].x * 8.0f, v[s].y * 8.0f, 0, false);
        p = __builtin_amdgcn_cvt_pk_fp8_f32(v[s].z * 8.0f, v[s].w * 8.0f, p, true);
        *(unsigned int*)(ob + off) = (unsigned int)p;
    }
}

// ---------------------------------------------------------------------------
// fp8 Gram, mfma_f32_32x32x16_fp8_fp8.
//
// r15 REDESIGN (post-mortem of r14's regression: FETCH 67->114 MB from lost
// XCD locality + lockstep barrier stalls from simultaneous persistent blocks):
//
// 1) XCD-local static packing: r = bb&7 (hw maps blockIdx%8 -> XCD, validated
//    by r13's 67 MB fetch floor). Each XCD owns r13's 8 strips
//    {r, 15-r, 16+r, 31-r, 32+r, 47-r, 48+r, 63-r} = 260 tiles (uniform in r).
//    Slot s = bb>>3 takes local tiles {2s, 2s+1}; leftovers 256+e -> slots
//    {0,33,66,99} (distinct CUs). Per-CU: 8 tiles, heavy CUs 9.
//
// 2) BARRIER-FREE K-loop via wave-private LDS: wave w (quadrant qi=w>>1,
//    qj=w&1) stages exactly its own operands -- A row-groups {2qi,2qi+1},
//    B groups {2qj,2qj+1}, 4 KB/chunk -- into a private double-buffered
//    8 KB region. Sync is the wave's own vmcnt only; no s_barrier in the
//    K-loop, so the 16 waves/CU free-run and cover each other's stalls.
//    WAR on restage is safe: the MFMAs consuming a buffer's ds_reads precede
//    the STAGE in program order (compiler's lgkmcnt waits retire the reads;
//    explicit lgkmcnt(0) added for belt-and-braces). L2->LDS traffic doubles
//    (2 waves stage each group) -- L2 has ~30x headroom. HBM unchanged.
//
// Triangle cover bi<=bj; diag blocks mask li>=lj -> rowsum == sum_neg.
__global__ __launch_bounds__(256, 4) void gram8_kernel(const u8* __restrict__ P8,
                                                       float* __restrict__ rowsum) {
    __shared__ u8 lds[4][2][4096];   // [wave][buf]: A0 @0, A1 @1024, B0 @2048, B1 @3072
    const int t = threadIdx.x, w = t >> 6, lane = t & 63;
    const int bb = blockIdx.x;
    const int r = bb & 7;            // XCD
    const int s = bb >> 3;           // slot within XCD [0,128)

    const int qi = w >> 1, qj = w & 1;

    int nt = 2, extra = 0;
    if (s == 0 || s == 33 || s == 66 || s == 99) { nt = 3; extra = 256 + s / 33; }

    f32x16 acc[2][2];
    long fa[2][2], fb[2][2];   // [k-step within chunk][tile]

#define STAGE(KC, BUF)                                                             \
    __builtin_amdgcn_global_load_lds(GLOBAL_AS(gA + (size_t)(KC) * 1024),          \
                                     LDS_AS(&lds[w][BUF][0]), 16, 0, 0);           \
    __builtin_amdgcn_global_load_lds(GLOBAL_AS(gA + (size_t)(KC) * 1024 + 32768),  \
                                     LDS_AS(&lds[w][BUF][1024]), 16, 0, 0);        \
    __builtin_amdgcn_global_load_lds(GLOBAL_AS(gB + (size_t)(KC) * 1024),          \
                                     LDS_AS(&lds[w][BUF][2048]), 16, 0, 0);        \
    __builtin_amdgcn_global_load_lds(GLOBAL_AS(gB + (size_t)(KC) * 1024 + 32768),  \
                                     LDS_AS(&lds[w][BUF][3072]), 16, 0, 0);

#define PF(KK, BUF)                                                                \
    fa[KK][0] = *(const long*)&lds[w][BUF][(KK) * 512 + lane * 8];                 \
    fa[KK][1] = *(const long*)&lds[w][BUF][1024 + (KK) * 512 + lane * 8];          \
    fb[KK][0] = *(const long*)&lds[w][BUF][2048 + (KK) * 512 + lane * 8];          \
    fb[KK][1] = *(const long*)&lds[w][BUF][3072 + (KK) * 512 + lane * 8];

#define MFMA4(KK)                                                                  \
    acc[0][0] = __builtin_amdgcn_mfma_f32_32x32x16_fp8_fp8(fa[KK][0], fb[KK][0], acc[0][0], 0, 0, 0); \
    acc[0][1] = __builtin_amdgcn_mfma_f32_32x32x16_fp8_fp8(fa[KK][0], fb[KK][1], acc[0][1], 0, 0, 0); \
    acc[1][0] = __builtin_amdgcn_mfma_f32_32x32x16_fp8_fp8(fa[KK][1], fb[KK][0], acc[1][0], 0, 0, 0); \
    acc[1][1] = __builtin_amdgcn_mfma_f32_32x32x16_fp8_fp8(fa[KK][1], fb[KK][1], acc[1][1], 0, 0, 0);

#define WAITV(N) asm volatile("s_waitcnt vmcnt(" #N ")" ::: "memory")
#define WAITL()  asm volatile("s_waitcnt lgkmcnt(0)" ::: "memory")

    for (int tt = 0; tt < nt; ++tt) {
        // XCD-local tile index -> (bi, bj) via strip walk (r13's cover)
        const int l = (tt == 2) ? extra : 2 * s + tt;
        int mm = l, bi = 0;
        #pragma unroll
        for (int s8 = 0; s8 < 8; ++s8) {
            const int strip = (s8 & 1) ? ((s8 >> 1) * 16 + 15 - r) : ((s8 >> 1) * 16 + r);
            const int n = 64 - strip;
            if (mm < n) { bi = strip; break; }
            mm -= n;
        }
        const int bj = bi + mm;
        const bool diag = (bi == bj);

        // wave-private operand bases (A groups 2qi/2qi+1, B groups 2qj/2qj+1)
        const u8* gA = P8 + (size_t)(bi * 4 + 2 * qi) * 32768 + lane * 16;
        const u8* gB = P8 + (size_t)(bj * 4 + 2 * qj) * 32768 + lane * 16;

        #pragma unroll
        for (int a = 0; a < 2; ++a)
            #pragma unroll
            for (int b = 0; b < 2; ++b)
                #pragma unroll
                for (int e = 0; e < 16; ++e) acc[a][b][e] = 0.0f;

        // WAR vs previous tile's epilogue LDS scratch (cross-wave); no-op at tt=0
        __syncthreads();

        // prologue: chunks 0,1 into bufs 0,1 (8 loads outstanding, per wave)
        STAGE(0, 0); STAGE(1, 1);

        int cur = 0;
        for (int kc = 0; kc < 30; ++kc) {
            WAITV(4);                 // oldest 4 = chunk kc resident
            PF(0, cur); PF(1, cur);
            MFMA4(0); MFMA4(1);
            WAITL();                  // ds_reads of buf `cur` retired
            STAGE(kc + 2, cur);       // refill just-consumed buffer
            cur ^= 1;
        }
        WAITV(4);                     // chunk 30
        PF(0, cur); PF(1, cur); MFMA4(0); MFMA4(1);
        cur ^= 1;
        WAITV(0);                     // chunk 31
        PF(0, cur); PF(1, cur); MFMA4(0); MFMA4(1);

        // epilogue: exp(acc*10/64), diag-block triangle mask, row/col partials.
        // C layout (32x32): col = lane&31, row = (reg&3) + 8*(reg>>2) + 4*(lane>>5)
        __syncthreads();                         // all waves done with their bufs
        float* rpart = (float*)&lds[0][0][0];
        float* cpart = (float*)&lds[0][0][512];
        if (t < 128) { rpart[t] = 0.0f; cpart[t] = 0.0f; }
        __syncthreads();
        const int half = lane >> 5, col = lane & 31;
        float csum[2] = {0.0f, 0.0f};
        #pragma unroll
        for (int ti = 0; ti < 2; ++ti) {
            float rs[16];
            #pragma unroll
            for (int reg = 0; reg < 16; ++reg) rs[reg] = 0.0f;
            #pragma unroll
            for (int tj = 0; tj < 2; ++tj) {
                const int lj = qj * 64 + tj * 32 + col;
                #pragma unroll
                for (int reg = 0; reg < 16; ++reg) {
                    const int li = qi * 64 + ti * 32 + (reg & 3) + 8 * (reg >> 2) + 4 * half;
                    float e = __expf(acc[ti][tj][reg] * INVT_SCALED);
                    if (diag && li >= lj) e = 0.0f;      // bi<bj blocks: always li<lj globally
                    rs[reg] += e;
                    csum[tj] += e;
                }
            }
            #pragma unroll
            for (int reg = 0; reg < 16; ++reg) {
                float v = rs[reg];
                v += __shfl_xor(v, 1); v += __shfl_xor(v, 2); v += __shfl_xor(v, 4);
                v += __shfl_xor(v, 8); v += __shfl_xor(v, 16);
                if (col == 0)
                    atomicAdd(&rpart[qi * 64 + ti * 32 + (reg & 3) + 8 * (reg >> 2) + 4 * half], v);
            }
        }
        #pragma unroll
        for (int tj = 0; tj < 2; ++tj) {
            float v = csum[tj];
            v += __shfl_xor(v, 32);
            if (half == 0) atomicAdd(&cpart[qj * 64 + tj * 32 + col], v);
        }
        __syncthreads();
        if (t < 128) atomicAdd(&rowsum[bi * 128 + t], rpart[t]);
        else         atomicAdd(&rowsum[bj * 128 + (t - 128)], cpart[t - 128]);
    }
}

// ---------------------------------------------------------------------------
// rowsum == sum_neg (diag + lower triangle excluded in gram)
__global__ __launch_bounds__(256) void final2_kernel(const float* __restrict__ rowsum,
                                                     float* __restrict__ out) {
    __shared__ float red[4];
    const int t = threadIdx.x;
    const int i = blockIdx.x * 256 + t;
    float v = logf(rowsum[i] * (1.0f / (float)(C - 1)));
    #pragma unroll
    for (int off = 32; off > 0; off >>= 1) v += __shfl_down(v, off);
    if ((t & 63) == 0) red[t >> 6] = v;
    __syncthreads();
    if (t == 0)
        atomicAdd(out, (red[0] + red[1] + red[2] + red[3]) * (1.0f / (float)C));
}

// ---------------------------------------------------------------------------
extern "C" void kernel_launch(void* const* d_in, const int* in_sizes, int n_in,
                              void* d_out, int out_size, void* d_ws, size_t ws_size,
                              hipStream_t stream) {
    const float* feat = (const float*)d_in[0];
    const int* labels = (const int*)d_in[1];
    const float* protos = (const float*)d_in[2];
    float* out = (float*)d_out;
    float* rowsum = (float*)d_ws;               // 32 KB
    u8* P8 = (u8*)((char*)d_ws + 32768);        // 8 MiB packed fp8 protos

    ema_split_kernel<<<C / 4, 256, 0, stream>>>(feat, labels, protos, P8, rowsum, out);
    gram8_kernel<<<1024, 256, 0, stream>>>(P8, rowsum);
    final2_kernel<<<C / 256, 256, 0, stream>>>(rowsum, out);
}

// Round 3
// 157.101 us; speedup vs baseline: 1.0744x; 1.0744x over previous
//
#include <hip/hip_runtime.h>
#include <math.h>

#define C 8192
#define D 1024
#define BATCH 1024
#define PM 0.95f
#define PMC 0.05f
// values pre-scaled by 8 before fp8 quant; dot comes out 64x too big.
// epilogue uses 10/64 = 0.15625 (exact in fp32).
#define INVT_SCALED 0.15625f

typedef unsigned char u8;
typedef __attribute__((ext_vector_type(16))) float f32x16;

#define GLOBAL_AS(p) ((const __attribute__((address_space(1))) void*)(p))
#define LDS_AS(p) ((__attribute__((address_space(3))) void*)(p))

// ---------------------------------------------------------------------------
// EMA + fp8 quantize, one wave per class (4 classes/block, 2048 blocks).
// Verified rounds 7-13. fp8 layout (512-B k-units for 32x32x16 fp8 MFMA):
//   element (row c, k) -> P8[(c>>5)*32768 + (k>>4)*512 + ((k>>3)&1)*256 + (c&31)*8 + (k&7)]
__global__ __launch_bounds__(256) void ema_split_kernel(const float* __restrict__ feat,
                                                        const int* __restrict__ labels,
                                                        const float* __restrict__ protos,
                                                        u8* __restrict__ P8,
                                                        float* __restrict__ rowsum,
                                                        float* __restrict__ out) {
    __shared__ int sl[BATCH];
    const int t = threadIdx.x, w = t >> 6, lane = t & 63;
    const int c = blockIdx.x * 4 + w;

    if (blockIdx.x < 32) rowsum[blockIdx.x * 256 + t] = 0.0f;
    if (blockIdx.x == 0 && t == 0) out[0] = 0.0f;

    for (int i = t; i < BATCH; i += 256) sl[i] = labels[i];
    __syncthreads();

    float4 v[4];
    #pragma unroll
    for (int s = 0; s < 4; ++s)
        v[s] = *(const float4*)(protos + (size_t)c * D + s * 256 + lane * 4);

    for (int base = 0; base < BATCH; base += 64) {
        unsigned long long mask = __ballot(sl[base + lane] == c);
        while (mask) {
            const int b = __ffsll((long long)mask) - 1;
            mask &= mask - 1;
            const int idx = base + b;
            float ss = 0.0f;
            #pragma unroll
            for (int s = 0; s < 4; ++s) {
                const float4 f = *(const float4*)(feat + (size_t)idx * D + s * 256 + lane * 4);
                v[s].x = v[s].x * PM + f.x * PMC;
                v[s].y = v[s].y * PM + f.y * PMC;
                v[s].z = v[s].z * PM + f.z * PMC;
                v[s].w = v[s].w * PM + f.w * PMC;
                ss += v[s].x * v[s].x + v[s].y * v[s].y + v[s].z * v[s].z + v[s].w * v[s].w;
            }
            #pragma unroll
            for (int off = 32; off > 0; off >>= 1) ss += __shfl_xor(ss, off);
            const float inv = 1.0f / fmaxf(sqrtf(ss), 1e-12f);
            #pragma unroll
            for (int s = 0; s < 4; ++s) {
                v[s].x *= inv; v[s].y *= inv; v[s].z *= inv; v[s].w *= inv;
            }
        }
    }

    u8* ob = P8 + (size_t)(c >> 5) * 32768 + (c & 31) * 8;
    #pragma unroll
    for (int s = 0; s < 4; ++s) {
        const int k0 = s * 256 + lane * 4;
        const size_t off = (size_t)(k0 >> 4) * 512 + ((k0 >> 3) & 1) * 256 + (k0 & 7);
        int p = __builtin_amdgcn_cvt_pk_fp8_f32(v[s].x * 8.0f, v[s].y * 8.0f, 0, false);
        p = __builtin_amdgcn_cvt_pk_fp8_f32(v[s].z * 8.0f, v[s].w * 8.0f, p, true);
        *(unsigned int*)(ob + off) = (unsigned int)p;
    }
}

// ---------------------------------------------------------------------------
// fp8 Gram, mfma_f32_32x32x16_fp8_fp8.
//
// r16: revert to r13's verified structure (2080 blocks, XCD strip swizzle,
// 5-buffer ring, block-shared staging, rolling dispatch gives ~90% packing
// already -- r14/r15 post-mortem: the "3 synchronized rounds" model was
// wrong). Change vs r13: K-loop period doubled to 2 chunks per sync point
// (16 barriers+waits per tile instead of 32; 16 MFMAs/wave per period).
// Ring discipline: period p consumes chunks 2p,2p+1 (bufs (2p)%5,(2p+1)%5),
// stages 2p+3,2p+4 into bufs consumed LAST period (one-barrier WAR
// separation, same as r13). WAITV(2) with 6 outstanding certifies chunks
// 2p+2,2p+3 for the next period -- vmcnt never drains to 0 in the main loop.
// Cross-barrier frag prefetch dropped: in the 2-chunk scheme it would read
// data certified only by the wave's OWN vmcnt (cross-wave race); all PFs sit
// after the barrier that makes all waves' stages visible. T5 setprio(1)
// wraps each MFMA cluster.
// Triangle cover bi<=bj (2080 blocks); diag blocks mask li>=lj ->
// rowsum == sum_neg. XCD swizzle: 260 blocks/XCD.
__global__ __launch_bounds__(256, 4) void gram8_kernel(const u8* __restrict__ P8,
                                                       float* __restrict__ rowsum) {
    __shared__ u8 lds[5][8192];      // per buf: A tiles 0..3 @ a*1024, B @ 4096+
    const int t = threadIdx.x, w = t >> 6, lane = t & 63;

    // swizzled block -> (bi, bj), bi <= bj, 128-row strips
    int mm = blockIdx.x >> 3;
    const int r = blockIdx.x & 7;
    int bi = 0;
    #pragma unroll
    for (int s = 0; s < 8; ++s) {
        const int strip = (s & 1) ? ((s >> 1) * 16 + 15 - r) : ((s >> 1) * 16 + r);
        const int n = 64 - strip;
        if (mm < n) { bi = strip; break; }
        mm -= n;
    }
    const int bj = bi + mm;
    const bool diag = (bi == bj);

    // per-wave staging: 2 glds x 1 KB per chunk (A tile w, B tile w)
    const u8* gsrcA = P8 + (size_t)(bi * 4 + w) * 32768 + lane * 16;
    const u8* gsrcB = P8 + (size_t)(bj * 4 + w) * 32768 + lane * 16;
    const int ldsA = w * 1024, ldsB = 4096 + w * 1024;

    const int qi = w >> 1, qj = w & 1;
    const int aoff = qi * 2048 + lane * 8;          // A tile base within buf
    const int boff = 4096 + qj * 2048 + lane * 8;   // B tile base within buf

    f32x16 acc[2][2];
    #pragma unroll
    for (int a = 0; a < 2; ++a)
        #pragma unroll
        for (int b = 0; b < 2; ++b)
            #pragma unroll
            for (int e = 0; e < 16; ++e) acc[a][b][e] = 0.0f;

    long fa[2][2], fb[2][2];   // [reg set][tile]

#define STAGE(KC, BUF)                                                         \
    __builtin_amdgcn_global_load_lds(GLOBAL_AS(gsrcA + (size_t)(KC) * 1024),   \
                                     LDS_AS(&lds[BUF][ldsA]), 16, 0, 0);       \
    __builtin_amdgcn_global_load_lds(GLOBAL_AS(gsrcB + (size_t)(KC) * 1024),   \
                                     LDS_AS(&lds[BUF][ldsB]), 16, 0, 0);

#define PF(SET, BUF, KK)                                                       \
    fa[SET][0] = *(const long*)&lds[BUF][aoff + (KK) * 512];                   \
    fa[SET][1] = *(const long*)&lds[BUF][aoff + 1024 + (KK) * 512];            \
    fb[SET][0] = *(const long*)&lds[BUF][boff + (KK) * 512];                   \
    fb[SET][1] = *(const long*)&lds[BUF][boff + 1024 + (KK) * 512];

#define MFMA4(SET)                                                             \
    acc[0][0] = __builtin_amdgcn_mfma_f32_32x32x16_fp8_fp8(fa[SET][0], fb[SET][0], acc[0][0], 0, 0, 0); \
    acc[0][1] = __builtin_amdgcn_mfma_f32_32x32x16_fp8_fp8(fa[SET][0], fb[SET][1], acc[0][1], 0, 0, 0); \
    acc[1][0] = __builtin_amdgcn_mfma_f32_32x32x16_fp8_fp8(fa[SET][1], fb[SET][0], acc[1][0], 0, 0, 0); \
    acc[1][1] = __builtin_amdgcn_mfma_f32_32x32x16_fp8_fp8(fa[SET][1], fb[SET][1], acc[1][1], 0, 0, 0);

#define WAITV(N) asm volatile("s_waitcnt vmcnt(" #N ")" ::: "memory")
#define SP1 __builtin_amdgcn_s_setprio(1)
#define SP0 __builtin_amdgcn_s_setprio(0)

    // prologue: stage chunks 0..2 into bufs 0..2 (6 glds outstanding/wave)
    STAGE(0, 0); STAGE(1, 1); STAGE(2, 2);
    WAITV(2);                                // chunks 0,1 resident
    __builtin_amdgcn_s_barrier();

    // main loop: period p consumes chunks 2p,2p+1; stages 2p+3,2p+4.
    // buf sequence: c0=(2p)%5 -> 0,2,4,1,3,0,...
    int c0 = 0;
    for (int p = 0; p < 14; ++p) {
        const int c1  = (c0 == 4) ? 0 : c0 + 1;
        const int nc0 = (c1 == 4) ? 0 : c1 + 1;       // buf of chunk 2p+2
        const int s0  = (nc0 == 4) ? 0 : nc0 + 1;     // (c0+3)%5: held 2p-2
        const int s1  = (s0 == 4) ? 0 : s0 + 1;       // (c0+4)%5: held 2p-1
        STAGE(2 * p + 3, s0);
        STAGE(2 * p + 4, s1);
        PF(0, c0, 0);                        // (2p, 0) - certified last barrier
        PF(1, c0, 1);                        // (2p, 1)
        SP1; MFMA4(0); SP0;
        PF(0, c1, 0);                        // (2p+1, 0)
        SP1; MFMA4(1); SP0;
        PF(1, c1, 1);                        // (2p+1, 1)
        SP1; MFMA4(0); SP0;
        SP1; MFMA4(1); SP0;
        WAITV(2);                            // certifies chunks 2p+2, 2p+3
        __builtin_amdgcn_s_barrier();
        c0 = nc0;
    }
    // peeled period 14: consume 28(buf3),29(buf4); stage 31 -> buf1 (held 26)
    STAGE(31, 1);
    PF(0, 3, 0); PF(1, 3, 1);
    SP1; MFMA4(0); SP0;
    PF(0, 4, 0);
    SP1; MFMA4(1); SP0;
    PF(1, 4, 1);
    SP1; MFMA4(0); SP0;
    SP1; MFMA4(1); SP0;
    WAITV(0);                                // chunks 30,31 resident (all drained)
    __builtin_amdgcn_s_barrier();
    // peeled period 15: consume 30(buf0), 31(buf1)
    PF(0, 0, 0); PF(1, 0, 1);
    SP1; MFMA4(0); SP0;
    PF(0, 1, 0);
    SP1; MFMA4(1); SP0;
    PF(1, 1, 1);
    SP1; MFMA4(0); SP0;
    SP1; MFMA4(1); SP0;

    // epilogue: exp(acc*10/64), diag-block triangle mask, row/col partials.
    // C layout (32x32): col = lane&31, row = (reg&3) + 8*(reg>>2) + 4*(lane>>5)
    __syncthreads();                         // K-loop fully done; lds reusable
    float* rpart = (float*)&lds[0][0];
    float* cpart = (float*)&lds[0][512];
    if (t < 128) { rpart[t] = 0.0f; cpart[t] = 0.0f; }
    __syncthreads();
    const int half = lane >> 5, col = lane & 31;
    float csum[2] = {0.0f, 0.0f};
    #pragma unroll
    for (int ti = 0; ti < 2; ++ti) {
        float rs[16];
        #pragma unroll
        for (int reg = 0; reg < 16; ++reg) rs[reg] = 0.0f;
        #pragma unroll
        for (int tj = 0; tj < 2; ++tj) {
            const int lj = qj * 64 + tj * 32 + col;
            #pragma unroll
            for (int reg = 0; reg < 16; ++reg) {
                const int li = qi * 64 + ti * 32 + (reg & 3) + 8 * (reg >> 2) + 4 * half;
                float e = __expf(acc[ti][tj][reg] * INVT_SCALED);
                if (diag && li >= lj) e = 0.0f;      // bi<bj blocks: always li<lj globally
                rs[reg] += e;
                csum[tj] += e;
            }
        }
        #pragma unroll
        for (int reg = 0; reg < 16; ++reg) {
            float v = rs[reg];
            v += __shfl_xor(v, 1); v += __shfl_xor(v, 2); v += __shfl_xor(v, 4);
            v += __shfl_xor(v, 8); v += __shfl_xor(v, 16);
            if (col == 0)
                atomicAdd(&rpart[qi * 64 + ti * 32 + (reg & 3) + 8 * (reg >> 2) + 4 * half], v);
        }
    }
    #pragma unroll
    for (int tj = 0; tj < 2; ++tj) {
        float v = csum[tj];
        v += __shfl_xor(v, 32);
        if (half == 0) atomicAdd(&cpart[qj * 64 + tj * 32 + col], v);
    }
    __syncthreads();
    if (t < 128) atomicAdd(&rowsum[bi * 128 + t], rpart[t]);
    else         atomicAdd(&rowsum[bj * 128 + (t - 128)], cpart[t - 128]);
}

// ---------------------------------------------------------------------------
// rowsum == sum_neg (diag + lower triangle excluded in gram)
__global__ __launch_bounds__(256) void final2_kernel(const float* __restrict__ rowsum,
                                                     float* __restrict__ out) {
    __shared__ float red[4];
    const int t = threadIdx.x;
    const int i = blockIdx.x * 256 + t;
    float v = logf(rowsum[i] * (1.0f / (float)(C - 1)));
    #pragma unroll
    for (int off = 32; off > 0; off >>= 1) v += __shfl_down(v, off);
    if ((t & 63) == 0) red[t >> 6] = v;
    __syncthreads();
    if (t == 0)
        atomicAdd(out, (red[0] + red[1] + red[2] + red[3]) * (1.0f / (float)C));
}

// ---------------------------------------------------------------------------
extern "C" void kernel_launch(void* const* d_in, const int* in_sizes, int n_in,
                              void* d_out, int out_size, void* d_ws, size_t ws_size,
                              hipStream_t stream) {
    const float* feat = (const float*)d_in[0];
    const int* labels = (const int*)d_in[1];
    const float* protos = (const float*)d_in[2];
    float* out = (float*)d_out;
    float* rowsum = (float*)d_ws;               // 32 KB
    u8* P8 = (u8*)((char*)d_ws + 32768);        // 8 MiB packed fp8 protos

    ema_split_kernel<<<C / 4, 256, 0, stream>>>(feat, labels, protos, P8, rowsum, out);
    gram8_kernel<<<2080, 256, 0, stream>>>(P8, rowsum);
    final2_kernel<<<C / 256, 256, 0, stream>>>(rowsum, out);
}

// Round 4
// 151.181 us; speedup vs baseline: 1.1165x; 1.0392x over previous
//
#include <hip/hip_runtime.h>
#include <math.h>

#define C 8192
#define D 1024
#define BATCH 1024
#define PM 0.95f
#define PMC 0.05f
// values pre-scaled by 8 before fp8 quant; dot comes out 64x too big.
// epilogue uses 10/64 = 0.15625 (exact in fp32).
#define INVT_SCALED 0.15625f

typedef unsigned char u8;
typedef __attribute__((ext_vector_type(16))) float f32x16;

#define GLOBAL_AS(p) ((const __attribute__((address_space(1))) void*)(p))
#define LDS_AS(p) ((__attribute__((address_space(3))) void*)(p))

// ---------------------------------------------------------------------------
// EMA + fp8 quantize.
//
// r17 REWRITE (theory: the old version's ~70 us hid in `total - gram8`):
// old version wrote P8 as per-lane scattered 4-byte stores, and each 128-B
// cache line of P8 holds pieces of 16 classes = 4 DIFFERENT blocks on 4
// different XCDs (round-robin dispatch) -> every line partially dirtied in
// 4 non-coherent L2s -> partial-sector eviction RMW traffic to HBM
// (~8 MB payload became ~50+ MB of random 32B RMW).
//
// New structure: 512 blocks x 16 consecutive classes (wave w owns classes
// cb+4w .. cb+4w+3, scanned sequentially -- per-class EMA order preserved).
// Quantized rows staged in LDS, then block-cooperative writeback: thread t
// stores 16 B covering 2 classes' 8-B pieces; each 128-B line is written
// exactly once, fully, from one block/L2. fp8 layout (unchanged, 512-B
// k-units for 32x32x16 fp8 MFMA):
//   element (row c, k) -> P8[(c>>5)*32768 + (k>>4)*512 + ((k>>3)&1)*256 + (c&31)*8 + (k&7)]
__global__ __launch_bounds__(256) void ema_split_kernel(const float* __restrict__ feat,
                                                        const int* __restrict__ labels,
                                                        const float* __restrict__ protos,
                                                        u8* __restrict__ P8,
                                                        float* __restrict__ rowsum,
                                                        float* __restrict__ out) {
    __shared__ int sl[BATCH];
    __shared__ unsigned int sq[128][16][2];   // [piece][class-in-block][half]  16 KB
    const int t = threadIdx.x, w = t >> 6, lane = t & 63;
    const int cb = blockIdx.x * 16;

    if (blockIdx.x < 32) rowsum[blockIdx.x * 256 + t] = 0.0f;
    if (blockIdx.x == 0 && t == 0) out[0] = 0.0f;

    for (int i = t; i < BATCH; i += 256) sl[i] = labels[i];
    __syncthreads();

    for (int i = 0; i < 4; ++i) {
        const int c = cb + w * 4 + i;

        float4 v[4];
        #pragma unroll
        for (int s = 0; s < 4; ++s)
            v[s] = *(const float4*)(protos + (size_t)c * D + s * 256 + lane * 4);

        for (int base = 0; base < BATCH; base += 64) {
            unsigned long long mask = __ballot(sl[base + lane] == c);
            while (mask) {
                const int b = __ffsll((long long)mask) - 1;
                mask &= mask - 1;
                const int idx = base + b;
                float ss = 0.0f;
                #pragma unroll
                for (int s = 0; s < 4; ++s) {
                    const float4 f = *(const float4*)(feat + (size_t)idx * D + s * 256 + lane * 4);
                    v[s].x = v[s].x * PM + f.x * PMC;
                    v[s].y = v[s].y * PM + f.y * PMC;
                    v[s].z = v[s].z * PM + f.z * PMC;
                    v[s].w = v[s].w * PM + f.w * PMC;
                    ss += v[s].x * v[s].x + v[s].y * v[s].y + v[s].z * v[s].z + v[s].w * v[s].w;
                }
                #pragma unroll
                for (int off = 32; off > 0; off >>= 1) ss += __shfl_xor(ss, off);
                const float inv = 1.0f / fmaxf(sqrtf(ss), 1e-12f);
                #pragma unroll
                for (int s = 0; s < 4; ++s) {
                    v[s].x *= inv; v[s].y *= inv; v[s].z *= inv; v[s].w *= inv;
                }
            }
        }

        // quantize into LDS staging: piece pp = (k0>>3) = s*32 + (lane>>1),
        // byte-half = lane&1  (k0 = s*256 + lane*4)
        #pragma unroll
        for (int s = 0; s < 4; ++s) {
            int p = __builtin_amdgcn_cvt_pk_fp8_f32(v[s].x * 8.0f, v[s].y * 8.0f, 0, false);
            p = __builtin_amdgcn_cvt_pk_fp8_f32(v[s].z * 8.0f, v[s].w * 8.0f, p, true);
            sq[s * 32 + (lane >> 1)][w * 4 + i][lane & 1] = (unsigned int)p;
        }
    }
    __syncthreads();

    // coalesced writeback: 1024 slots of 16 B (piece pp, class pair 2a,2a+1);
    // dst 16B-aligned; each 128-B line (16 classes x 8 B) fully covered by
    // this block. (cb&31) in {0,16} -> +0 or +128 within the 256-B subunit.
    u8* base = P8 + (size_t)(cb >> 5) * 32768 + (cb & 31) * 8;
    #pragma unroll
    for (int it = 0; it < 4; ++it) {
        const int slot = it * 256 + t;
        const int pp = slot >> 3, a = slot & 7;
        uint4 val;
        val.x = sq[pp][2 * a][0];     val.y = sq[pp][2 * a][1];
        val.z = sq[pp][2 * a + 1][0]; val.w = sq[pp][2 * a + 1][1];
        *(uint4*)(base + (pp >> 1) * 512 + (pp & 1) * 256 + a * 16) = val;
    }
}

// ---------------------------------------------------------------------------
// fp8 Gram, mfma_f32_32x32x16_fp8_fp8. r13 verbatim (best known: 75.4 us) --
// r14/r15/r16 structural variants all regressed; rolling dispatch already
// packs the 2080-block grid to ~90%. Deep pipeline: 5 LDS buffers, 40 KB,
// oldest-2 vmcnt waits, 4 blocks/CU, register-level fragment prefetch (two
// frag sets; during MFMAs of K-step s, ds_reads for s+1 already in flight).
// Certification: vmcnt(4) at barrier kc certifies chunks kc AND kc+1 (oldest
// 4 of 8 outstanding), so prefetching chunk kc+1's first step during period
// kc is legal. WAR: buffer staged at period kc held chunk kc-1, last read
// (prefetch) pre-barrier-kc -> one full barrier separation.
// Triangle cover bi<=bj (2080 blocks); diag blocks mask li>=lj ->
// rowsum == sum_neg. XCD swizzle: 260 blocks/XCD.
__global__ __launch_bounds__(256, 4) void gram8_kernel(const u8* __restrict__ P8,
                                                       float* __restrict__ rowsum) {
    __shared__ u8 lds[5][8192];      // per buf: A tiles 0..3 @ a*1024, B @ 4096+
    const int t = threadIdx.x, w = t >> 6, lane = t & 63;

    // swizzled block -> (bi, bj), bi <= bj, 128-row strips
    int mm = blockIdx.x >> 3;
    const int r = blockIdx.x & 7;
    int bi = 0;
    #pragma unroll
    for (int s = 0; s < 8; ++s) {
        const int strip = (s & 1) ? ((s >> 1) * 16 + 15 - r) : ((s >> 1) * 16 + r);
        const int n = 64 - strip;
        if (mm < n) { bi = strip; break; }
        mm -= n;
    }
    const int bj = bi + mm;
    const bool diag = (bi == bj);

    // per-wave staging: 2 glds x 1 KB per chunk (A tile w, B tile w)
    const u8* gsrcA = P8 + (size_t)(bi * 4 + w) * 32768 + lane * 16;
    const u8* gsrcB = P8 + (size_t)(bj * 4 + w) * 32768 + lane * 16;
    const int ldsA = w * 1024, ldsB = 4096 + w * 1024;

    const int qi = w >> 1, qj = w & 1;
    const int aoff = qi * 2048 + lane * 8;          // A tile base within buf
    const int boff = 4096 + qj * 2048 + lane * 8;   // B tile base within buf

    f32x16 acc[2][2];
    #pragma unroll
    for (int a = 0; a < 2; ++a)
        #pragma unroll
        for (int b = 0; b < 2; ++b)
            #pragma unroll
            for (int e = 0; e < 16; ++e) acc[a][b][e] = 0.0f;

    long fa[2][2], fb[2][2];   // [reg set][tile]

#define STAGE(KC, BUF)                                                         \
    __builtin_amdgcn_global_load_lds(GLOBAL_AS(gsrcA + (size_t)(KC) * 1024),   \
                                     LDS_AS(&lds[BUF][ldsA]), 16, 0, 0);       \
    __builtin_amdgcn_global_load_lds(GLOBAL_AS(gsrcB + (size_t)(KC) * 1024),   \
                                     LDS_AS(&lds[BUF][ldsB]), 16, 0, 0);

#define PF(SET, BUF, KK)                                                       \
    fa[SET][0] = *(const long*)&lds[BUF][aoff + (KK) * 512];                   \
    fa[SET][1] = *(const long*)&lds[BUF][aoff + 1024 + (KK) * 512];            \
    fb[SET][0] = *(const long*)&lds[BUF][boff + (KK) * 512];                   \
    fb[SET][1] = *(const long*)&lds[BUF][boff + 1024 + (KK) * 512];

#define MFMA4(SET)                                                             \
    acc[0][0] = __builtin_amdgcn_mfma_f32_32x32x16_fp8_fp8(fa[SET][0], fb[SET][0], acc[0][0], 0, 0, 0); \
    acc[0][1] = __builtin_amdgcn_mfma_f32_32x32x16_fp8_fp8(fa[SET][0], fb[SET][1], acc[0][1], 0, 0, 0); \
    acc[1][0] = __builtin_amdgcn_mfma_f32_32x32x16_fp8_fp8(fa[SET][1], fb[SET][0], acc[1][0], 0, 0, 0); \
    acc[1][1] = __builtin_amdgcn_mfma_f32_32x32x16_fp8_fp8(fa[SET][1], fb[SET][1], acc[1][1], 0, 0, 0);

#define WAITV(N) asm volatile("s_waitcnt vmcnt(" #N ")" ::: "memory")

    // prologue: stage chunks 0..3 into bufs 0..3 (8 glds outstanding/wave)
    STAGE(0, 0); STAGE(1, 1); STAGE(2, 2); STAGE(3, 3);
    WAITV(4);                                // chunks 0,1 resident
    __builtin_amdgcn_s_barrier();
    PF(0, 0, 0);                             // step 0 (chunk 0, kk=0)

    int cb = 0;                              // buffer of chunk kc (kc % 5)
    for (int kc = 0; kc < 28; ++kc) {
        const int sb = (cb >= 1) ? cb - 1 : 4;       // (kc+4) % 5
        STAGE(kc + 4, sb);
        const int nb = (cb == 4) ? 0 : cb + 1;       // buffer of chunk kc+1
        PF(1, cb, 1);                        // step 2kc+1 (same chunk)
        MFMA4(0);                            // step 2kc
        PF(0, nb, 0);                        // step 2kc+2 (chunk kc+1 - certified)
        MFMA4(1);                            // step 2kc+1
        WAITV(4);                            // certifies chunks kc+1, kc+2
        __builtin_amdgcn_s_barrier();
        cb = nb;
    }
    // peeled tail (cb == 3): chunks 28..31 in bufs 3,4,0,1
    PF(1, 3, 1); MFMA4(0);                   // steps 56/57
    PF(0, 4, 0); MFMA4(1);
    WAITV(2); __builtin_amdgcn_s_barrier();  // certifies chunk 30
    PF(1, 4, 1); MFMA4(0);                   // steps 58/59
    PF(0, 0, 0); MFMA4(1);
    WAITV(0); __builtin_amdgcn_s_barrier();  // certifies chunk 31
    PF(1, 0, 1); MFMA4(0);                   // steps 60/61
    PF(0, 1, 0); MFMA4(1);
    PF(1, 1, 1); MFMA4(0);                   // steps 62/63
    MFMA4(1);

    // epilogue: exp(acc*10/64), diag-block triangle mask, row/col partials.
    // C layout (32x32): col = lane&31, row = (reg&3) + 8*(reg>>2) + 4*(lane>>5)
    __syncthreads();                         // K-loop fully done; lds reusable
    float* rpart = (float*)&lds[0][0];
    float* cpart = (float*)&lds[0][512];
    if (t < 128) { rpart[t] = 0.0f; cpart[t] = 0.0f; }
    __syncthreads();
    const int half = lane >> 5, col = lane & 31;
    float csum[2] = {0.0f, 0.0f};
    #pragma unroll
    for (int ti = 0; ti < 2; ++ti) {
        float rs[16];
        #pragma unroll
        for (int reg = 0; reg < 16; ++reg) rs[reg] = 0.0f;
        #pragma unroll
        for (int tj = 0; tj < 2; ++tj) {
            const int lj = qj * 64 + tj * 32 + col;
            #pragma unroll
            for (int reg = 0; reg < 16; ++reg) {
                const int li = qi * 64 + ti * 32 + (reg & 3) + 8 * (reg >> 2) + 4 * half;
                float e = __expf(acc[ti][tj][reg] * INVT_SCALED);
                if (diag && li >= lj) e = 0.0f;      // bi<bj blocks: always li<lj globally
                rs[reg] += e;
                csum[tj] += e;
            }
        }
        #pragma unroll
        for (int reg = 0; reg < 16; ++reg) {
            float v = rs[reg];
            v += __shfl_xor(v, 1); v += __shfl_xor(v, 2); v += __shfl_xor(v, 4);
            v += __shfl_xor(v, 8); v += __shfl_xor(v, 16);
            if (col == 0)
                atomicAdd(&rpart[qi * 64 + ti * 32 + (reg & 3) + 8 * (reg >> 2) + 4 * half], v);
        }
    }
    #pragma unroll
    for (int tj = 0; tj < 2; ++tj) {
        float v = csum[tj];
        v += __shfl_xor(v, 32);
        if (half == 0) atomicAdd(&cpart[qj * 64 + tj * 32 + col], v);
    }
    __syncthreads();
    if (t < 128) atomicAdd(&rowsum[bi * 128 + t], rpart[t]);
    else         atomicAdd(&rowsum[bj * 128 + (t - 128)], cpart[t - 128]);
}

// ---------------------------------------------------------------------------
// rowsum == sum_neg (diag + lower triangle excluded in gram)
__global__ __launch_bounds__(256) void final2_kernel(const float* __restrict__ rowsum,
                                                     float* __restrict__ out) {
    __shared__ float red[4];
    const int t = threadIdx.x;
    const int i = blockIdx.x * 256 + t;
    float v = logf(rowsum[i] * (1.0f / (float)(C - 1)));
    #pragma unroll
    for (int off = 32; off > 0; off >>= 1) v += __shfl_down(v, off);
    if ((t & 63) == 0) red[t >> 6] = v;
    __syncthreads();
    if (t == 0)
        atomicAdd(out, (red[0] + red[1] + red[2] + red[3]) * (1.0f / (float)C));
}

// ---------------------------------------------------------------------------
extern "C" void kernel_launch(void* const* d_in, const int* in_sizes, int n_in,
                              void* d_out, int out_size, void* d_ws, size_t ws_size,
                              hipStream_t stream) {
    const float* feat = (const float*)d_in[0];
    const int* labels = (const int*)d_in[1];
    const float* protos = (const float*)d_in[2];
    float* out = (float*)d_out;
    float* rowsum = (float*)d_ws;               // 32 KB
    u8* P8 = (u8*)((char*)d_ws + 32768);        // 8 MiB packed fp8 protos

    ema_split_kernel<<<C / 16, 256, 0, stream>>>(feat, labels, protos, P8, rowsum, out);
    gram8_kernel<<<2080, 256, 0, stream>>>(P8, rowsum);
    final2_kernel<<<C / 256, 256, 0, stream>>>(rowsum, out);
}